// Round 2
// 362.181 us; speedup vs baseline: 1.0376x; 1.0376x over previous
//
#include <hip/hip_runtime.h>
#include <math.h>

#define NPART 32768
#define MS 50
#define BLOCK 256

typedef __attribute__((ext_vector_type(8))) short bfrag;   // 8 bf16 (4 VGPRs)
typedef __attribute__((ext_vector_type(4))) float ffrag;   // 4 fp32 (MFMA C/D)

// float -> bf16 bits, round-to-nearest-even (init-time staging only)
__device__ __forceinline__ unsigned short f2bf(float x) {
    unsigned u = __float_as_uint(x);
    u += 0x7fffu + ((u >> 16) & 1u);
    return (unsigned short)(u >> 16);
}

// Hot-loop pack: single HW instruction (gfx950 has v_cvt_pk_bf16_f32 but NO
// builtin for it — learn_hip m240). RNE, matches f2bf bit-exactly.
// lo 16 bits = bf16(a), hi 16 bits = bf16(b).
__device__ __forceinline__ unsigned pk2(float a, float b) {
    unsigned r;
    asm("v_cvt_pk_bf16_f32 %0, %1, %2" : "=v"(r) : "v"(a), "v"(b));
    return r;
}

// tanh(x) = 1 - 2/(exp(2x)+1); saturates correctly at +/-inf.
__device__ __forceinline__ float fast_tanh(float x) {
    float e = __expf(2.0f * x);
    return 1.0f - __fdividef(2.0f, e + 1.0f);
}

// One wave = 16 particles (p = lane&15, q = lane>>4). Lane owns X dims
// [8q,8q+8) of particle p == B-layout of mfma_f32_16x16x32_bf16.
//
// GEMM1: H(128x16) = W1x @ X + C-init(static fold).
//   C-layout: lane(p,q), tile mt, reg r holds H[16mt+4q+r][particle p].
//
// GEMM2 *layout trick*: computed as Z^T(16x32) = H^T(16x16...) with H as the
// A-OPERAND. A-layout A[m=lane&15][k=8q+j] has the same 16-index (=particle)
// mapping as GEMM1's C-output column, so the tanh'd C-regs feed GEMM2
// directly: A-frag(kt) element j = C[2kt+(j>>2)][j&3], which holds hidden
// unit kappa = 32kt+16(j>>2)+4q+(j&3). W2's B-frags are loaded kappa-permuted
// at init so the contraction is exact. NO H LDS round-trip, NO barrier.
// D-output: lane(p,q) reg r = Z[particle 4q+r][outdim 16nt+p]; a small
// scatter/gather through LDS returns Z to the X-update (B-) layout.
__global__ __launch_bounds__(BLOCK, 2)
void fused_sde_mfma(const float* __restrict__ obs,
                    const float* __restrict__ x0,
                    const float* __restrict__ v0,
                    const float* __restrict__ noise,
                    const float* __restrict__ gW1,
                    const float* __restrict__ gb1,
                    const float* __restrict__ gW2,
                    const float* __restrict__ gb2,
                    const float* __restrict__ gtheta,
                    const int* __restrict__ gobs_idx,
                    const int* __restrict__ gctrl,
                    float* __restrict__ outX,
                    float* __restrict__ outV)
{
    // Zlds[wave][particle][dim], pitch 36 floats (144 B) -> <=2-way aliasing.
    __shared__ __align__(16) float Zlds[4][16][36];

    const int tid  = threadIdx.x;
    const int w    = tid >> 6;
    const int lane = tid & 63;
    const int p    = lane & 15;
    const int q    = lane >> 4;
    const int part = blockIdx.x * 64 + w * 16 + p;

    const float theta = gtheta[0];
    const float tfeat = (float)gobs_idx[0];
    const float cr    = (float)gctrl[0];
    const float dt      = 1.0f / (float)MS;
    const float sqrt_dt = sqrtf(dt);
    const float ax  = 1.0f - dt * theta;
    const float bcr = dt * cr;
    const float kv  = dt * (0.5f - cr);

    // ---- GEMM1 A-fragments: W1 X-block (features 0..31) ----
    bfrag A1[8];
    #pragma unroll
    for (int mt = 0; mt < 8; ++mt) {
        const int h = 16 * mt + p;
        bfrag a;
        #pragma unroll
        for (int j = 0; j < 8; ++j)
            a[j] = (short)f2bf(gW1[(8 * q + j) * 128 + h]);
        A1[mt] = a;
    }

    // ---- GEMM2 B-fragments: W2 rows kappa-permuted, cols = outdim 16nt+p ----
    bfrag B2[2][4];
    #pragma unroll
    for (int nt = 0; nt < 2; ++nt) {
        #pragma unroll
        for (int kt = 0; kt < 4; ++kt) {
            bfrag b;
            #pragma unroll
            for (int j = 0; j < 8; ++j) {
                const int h = 32 * kt + 16 * (j >> 2) + 4 * q + (j & 3);  // kappa
                b[j] = (short)f2bf(gW2[h * 32 + 16 * nt + p]);
            }
            B2[nt][kt] = b;
        }
    }

    // ---- static C-init for GEMM1: Stat[h] = b1 + Y.W1y + t*W1t ; W1s[h] ----
    ffrag Stat[8], W1s[8];
    #pragma unroll
    for (int mt = 0; mt < 8; ++mt) {
        #pragma unroll
        for (int r = 0; r < 4; ++r) {
            const int h = 16 * mt + 4 * q + r;
            float acc = gb1[h];
            #pragma unroll
            for (int j = 0; j < 8; ++j)
                acc = fmaf(obs[j], gW1[(32 + j) * 128 + h], acc);
            acc = fmaf(tfeat, gW1[41 * 128 + h], acc);
            Stat[mt][r] = acc;
            W1s[mt][r]  = gW1[40 * 128 + h];
        }
    }

    // GEMM2 C-init: b2[outdim 16nt+p], broadcast across the 4 particle-rows.
    const float bz0 = gb2[p], bz1 = gb2[16 + p];
    const ffrag Z0i = ffrag{bz0, bz0, bz0, bz0};
    const ffrag Z1i = ffrag{bz1, bz1, bz1, bz1};
    const ffrag Zzero = ffrag{0.f, 0.f, 0.f, 0.f};

    // ---- per-lane state ----
    float X[8];
    {
        const float4* xp = (const float4*)(x0 + (size_t)part * 32 + 8 * q);
        float4 a = xp[0], b = xp[1];
        X[0] = a.x; X[1] = a.y; X[2] = a.z; X[3] = a.w;
        X[4] = b.x; X[5] = b.y; X[6] = b.z; X[7] = b.w;
    }
    float V = v0[part];

    const float* nbase = noise + (size_t)part * 32 + 8 * q;
    float4 nc0 = ((const float4*)nbase)[0];
    float4 nc1 = ((const float4*)nbase)[1];

    float* zbase = &Zlds[w][0][0];
    const float* zrow = &Zlds[w][p][0];

    #pragma unroll 1
    for (int m = 0; m < MS; ++m) {
        const int mn = (m + 1 < MS) ? m + 1 : m;
        const float* np = nbase + (size_t)mn * ((size_t)NPART * 32);
        float4 nn0 = ((const float4*)np)[0];
        float4 nn1 = ((const float4*)np)[1];

        // B fragment: X -> packed bf16 (1 v_cvt_pk_bf16_f32 per pair)
        int4 bxw = make_int4((int)pk2(X[0], X[1]), (int)pk2(X[2], X[3]),
                             (int)pk2(X[4], X[5]), (int)pk2(X[6], X[7]));
        bfrag BX = __builtin_bit_cast(bfrag, bxw);

        const float s = (float)m * dt;

        // ---- GEMM1: 8 independent MFMAs, C-init ready at step start ----
        ffrag C[8];
        #pragma unroll
        for (int mt = 0; mt < 8; ++mt) {
            ffrag c;
            #pragma unroll
            for (int r = 0; r < 4; ++r) c[r] = fmaf(s, W1s[mt][r], Stat[mt][r]);
            C[mt] = c;
        }
        #pragma unroll
        for (int mt = 0; mt < 8; ++mt)
            C[mt] = __builtin_amdgcn_mfma_f32_16x16x32_bf16(A1[mt], BX, C[mt], 0, 0, 0);

        // ---- tanh + pack: C-regs become GEMM2 A-fragments directly ----
        uint2 Hpk[8];
        #pragma unroll
        for (int mt = 0; mt < 8; ++mt) {
            const unsigned u0 = pk2(fast_tanh(C[mt][0]), fast_tanh(C[mt][1]));
            const unsigned u1 = pk2(fast_tanh(C[mt][2]), fast_tanh(C[mt][3]));
            Hpk[mt] = make_uint2(u0, u1);
        }

        // ---- GEMM2: Z^T = H^T @ W2(kappa), two 2-deep chains per N-tile ----
        ffrag D0a = Z0i, D0b = Zzero, D1a = Z1i, D1b = Zzero;
        #pragma unroll
        for (int kt = 0; kt < 4; ++kt) {
            int4 aw = make_int4((int)Hpk[2 * kt].x, (int)Hpk[2 * kt].y,
                                (int)Hpk[2 * kt + 1].x, (int)Hpk[2 * kt + 1].y);
            bfrag A = __builtin_bit_cast(bfrag, aw);
            if (kt & 1) {
                D0b = __builtin_amdgcn_mfma_f32_16x16x32_bf16(A, B2[0][kt], D0b, 0, 0, 0);
                D1b = __builtin_amdgcn_mfma_f32_16x16x32_bf16(A, B2[1][kt], D1b, 0, 0, 0);
            } else {
                D0a = __builtin_amdgcn_mfma_f32_16x16x32_bf16(A, B2[0][kt], D0a, 0, 0, 0);
                D1a = __builtin_amdgcn_mfma_f32_16x16x32_bf16(A, B2[1][kt], D1a, 0, 0, 0);
            }
        }
        ffrag D0 = D0a + D0b;   // Z[particle 4q+r][outdim p]
        ffrag D1 = D1a + D1b;   // Z[particle 4q+r][outdim 16+p]

        // ---- scatter Z to [particle][dim], gather back in B-layout ----
        #pragma unroll
        for (int r = 0; r < 4; ++r) {
            float* zr = zbase + (4 * q + r) * 36;
            zr[p]      = D0[r];     // compiler fuses into ds_write2_b32
            zr[16 + p] = D1[r];
        }

        __builtin_amdgcn_wave_barrier();   // DS in-order per wave

        float4 z0 = *(const float4*)&zrow[8 * q];
        float4 z1 = *(const float4*)&zrow[8 * q + 4];
        float Z[8] = {z0.x, z0.y, z0.z, z0.w, z1.x, z1.y, z1.z, z1.w};
        float Nn[8] = {nc0.x, nc0.y, nc0.z, nc0.w, nc1.x, nc1.y, nc1.z, nc1.w};

        // V: (0.5-cr)*dt*sum(Z^2) + sqrt_dt*sum(Z*n)
        float s2 = 0.0f, sn = 0.0f;
        #pragma unroll
        for (int j = 0; j < 8; ++j) {
            s2 = fmaf(Z[j], Z[j], s2);
            sn = fmaf(Z[j], Nn[j], sn);
        }
        s2 += __shfl_xor(s2, 16); s2 += __shfl_xor(s2, 32);
        sn += __shfl_xor(sn, 16); sn += __shfl_xor(sn, 32);
        V = fmaf(kv, s2, fmaf(sqrt_dt, sn, V));

        // X = ax*X - bcr*Z + sqrt_dt*n
        #pragma unroll
        for (int j = 0; j < 8; ++j) {
            float t = fmaf(-bcr, Z[j], sqrt_dt * Nn[j]);
            X[j] = fmaf(ax, X[j], t);
        }

        nc0 = nn0; nc1 = nn1;

        __builtin_amdgcn_wave_barrier();   // protect Zlds WAR before next scatter
    }

    float4* xout = (float4*)(outX + (size_t)part * 32 + 8 * q);
    xout[0] = make_float4(X[0], X[1], X[2], X[3]);
    xout[1] = make_float4(X[4], X[5], X[6], X[7]);
    if (q == 0) outV[part] = V;
}

extern "C" void kernel_launch(void* const* d_in, const int* in_sizes, int n_in,
                              void* d_out, int out_size, void* d_ws, size_t ws_size,
                              hipStream_t stream) {
    const float* obs   = (const float*)d_in[0];
    const float* x0    = (const float*)d_in[1];
    const float* v0    = (const float*)d_in[2];
    const float* noise = (const float*)d_in[3];
    const float* W1    = (const float*)d_in[4];
    const float* b1    = (const float*)d_in[5];
    const float* W2    = (const float*)d_in[6];
    const float* b2    = (const float*)d_in[7];
    const float* th    = (const float*)d_in[8];
    const int*   oi    = (const int*)d_in[9];
    const int*   cr    = (const int*)d_in[10];

    float* outX = (float*)d_out;
    float* outV = outX + (size_t)NPART * 32;

    dim3 grid(NPART / 64);   // 512 blocks x 4 waves x 16 particles
    fused_sde_mfma<<<grid, BLOCK, 0, stream>>>(obs, x0, v0, noise, W1, b1, W2, b2,
                                               th, oi, cr, outX, outV);
}

// Round 3
// 313.215 us; speedup vs baseline: 1.1998x; 1.1563x over previous
//
#include <hip/hip_runtime.h>
#include <math.h>

#define NPART 32768
#define MS 50
#define BLOCK 256

typedef __attribute__((ext_vector_type(8))) short bfrag;   // 8 bf16 (4 VGPRs)
typedef __attribute__((ext_vector_type(4))) float ffrag;   // 4 fp32 (MFMA C/D)

// float -> bf16 bits, round-to-nearest-even (init-time staging only)
__device__ __forceinline__ unsigned short f2bf(float x) {
    unsigned u = __float_as_uint(x);
    u += 0x7fffu + ((u >> 16) & 1u);
    return (unsigned short)(u >> 16);
}

// Hot-loop pack: single HW instruction (gfx950 has v_cvt_pk_bf16_f32 but NO
// builtin for it — learn_hip m240). RNE, matches f2bf bit-exactly.
__device__ __forceinline__ unsigned pk2(float a, float b) {
    unsigned r;
    asm("v_cvt_pk_bf16_f32 %0, %1, %2" : "=v"(r) : "v"(a), "v"(b));
    return r;
}

// Guaranteed-native transcendentals: v_exp_f32 computes 2^x, v_rcp_f32 = 1/x.
__device__ __forceinline__ float nexp2(float x) {
#if __has_builtin(__builtin_amdgcn_exp2f)
    return __builtin_amdgcn_exp2f(x);
#else
    float r;
    asm("v_exp_f32 %0, %1" : "=v"(r) : "v"(x));
    return r;
#endif
}
__device__ __forceinline__ float nrcp(float x) {
#if __has_builtin(__builtin_amdgcn_rcpf)
    return __builtin_amdgcn_rcpf(x);
#else
    float r;
    asm("v_rcp_f32 %0, %1" : "=v"(r) : "v"(x));
    return r;
#endif
}

// tanh(x) = 1 - 2/(2^(2*log2e*x)+1). Exactly 5 VALU ops (mul,exp,add,rcp,fma).
// Saturates correctly: x->+inf: e=inf, rcp=0, ->1. x->-inf: e=0, ->-1.
__device__ __forceinline__ float fast_tanh(float x) {
    const float c = 2.8853900817779268f;   // 2*log2(e)
    float e = nexp2(x * c);
    float r = nrcp(e + 1.0f);
    return fmaf(-2.0f, r, 1.0f);
}

// One wave = 16 particles (p = lane&15, q = lane>>4). Lane owns X dims
// [8q,8q+8) of particle p == B-layout of mfma_f32_16x16x32_bf16.
//
// GEMM1: H(128x16) = W1x @ X + C-init(static fold).
//   C-layout: lane(p,q), tile mt, reg r holds H[16mt+4q+r][particle p].
//
// GEMM2 *layout trick*: computed as Z^T(16x32) = H^T(16x16...) with H as the
// A-OPERAND. A-layout A[m=lane&15][k=8q+j] has the same 16-index (=particle)
// mapping as GEMM1's C-output column, so the tanh'd C-regs feed GEMM2
// directly: A-frag(kt) element j = C[2kt+(j>>2)][j&3], which holds hidden
// unit kappa = 32kt+16(j>>2)+4q+(j&3). W2's B-frags are loaded kappa-permuted
// at init so the contraction is exact. NO H LDS round-trip, NO barrier.
// D-output: lane(p,q) reg r = Z[particle 4q+r][outdim 16nt+p]; a small
// scatter/gather through LDS returns Z to the X-update (B-) layout.
__global__ __launch_bounds__(BLOCK, 2)
void fused_sde_mfma(const float* __restrict__ obs,
                    const float* __restrict__ x0,
                    const float* __restrict__ v0,
                    const float* __restrict__ noise,
                    const float* __restrict__ gW1,
                    const float* __restrict__ gb1,
                    const float* __restrict__ gW2,
                    const float* __restrict__ gb2,
                    const float* __restrict__ gtheta,
                    const int* __restrict__ gobs_idx,
                    const int* __restrict__ gctrl,
                    float* __restrict__ outX,
                    float* __restrict__ outV)
{
    // Zlds[wave][particle][dim], pitch 36 floats (144 B) -> <=2-way aliasing.
    __shared__ __align__(16) float Zlds[4][16][36];

    const int tid  = threadIdx.x;
    const int w    = tid >> 6;
    const int lane = tid & 63;
    const int p    = lane & 15;
    const int q    = lane >> 4;
    const int part = blockIdx.x * 64 + w * 16 + p;

    const float theta = gtheta[0];
    const float tfeat = (float)gobs_idx[0];
    const float cr    = (float)gctrl[0];
    const float dt      = 1.0f / (float)MS;
    const float sqrt_dt = sqrtf(dt);
    const float ax  = 1.0f - dt * theta;
    const float bcr = dt * cr;
    const float kv  = dt * (0.5f - cr);

    // ---- GEMM1 A-fragments: W1 X-block (features 0..31) ----
    bfrag A1[8];
    #pragma unroll
    for (int mt = 0; mt < 8; ++mt) {
        const int h = 16 * mt + p;
        bfrag a;
        #pragma unroll
        for (int j = 0; j < 8; ++j)
            a[j] = (short)f2bf(gW1[(8 * q + j) * 128 + h]);
        A1[mt] = a;
    }

    // ---- GEMM2 B-fragments: W2 rows kappa-permuted, cols = outdim 16nt+p ----
    bfrag B2[2][4];
    #pragma unroll
    for (int nt = 0; nt < 2; ++nt) {
        #pragma unroll
        for (int kt = 0; kt < 4; ++kt) {
            bfrag b;
            #pragma unroll
            for (int j = 0; j < 8; ++j) {
                const int h = 32 * kt + 16 * (j >> 2) + 4 * q + (j & 3);  // kappa
                b[j] = (short)f2bf(gW2[h * 32 + 16 * nt + p]);
            }
            B2[nt][kt] = b;
        }
    }

    // ---- static C-init for GEMM1: Stat[h] = b1 + Y.W1y + t*W1t ; W1s[h] ----
    ffrag Stat[8], W1s[8];
    #pragma unroll
    for (int mt = 0; mt < 8; ++mt) {
        #pragma unroll
        for (int r = 0; r < 4; ++r) {
            const int h = 16 * mt + 4 * q + r;
            float acc = gb1[h];
            #pragma unroll
            for (int j = 0; j < 8; ++j)
                acc = fmaf(obs[j], gW1[(32 + j) * 128 + h], acc);
            acc = fmaf(tfeat, gW1[41 * 128 + h], acc);
            Stat[mt][r] = acc;
            W1s[mt][r]  = gW1[40 * 128 + h];
        }
    }

    // GEMM2 C-init: b2[outdim 16nt+p], broadcast across the 4 particle-rows.
    const float bz0 = gb2[p], bz1 = gb2[16 + p];
    const ffrag Z0i = ffrag{bz0, bz0, bz0, bz0};
    const ffrag Z1i = ffrag{bz1, bz1, bz1, bz1};
    const ffrag Zzero = ffrag{0.f, 0.f, 0.f, 0.f};

    // ---- per-lane state ----
    float X[8];
    {
        const float4* xp = (const float4*)(x0 + (size_t)part * 32 + 8 * q);
        float4 a = xp[0], b = xp[1];
        X[0] = a.x; X[1] = a.y; X[2] = a.z; X[3] = a.w;
        X[4] = b.x; X[5] = b.y; X[6] = b.z; X[7] = b.w;
    }
    float V = v0[part];

    const float* nbase = noise + (size_t)part * 32 + 8 * q;
    float4 nc0 = ((const float4*)nbase)[0];
    float4 nc1 = ((const float4*)nbase)[1];

    float* zbase = &Zlds[w][0][0];
    const float* zrow = &Zlds[w][p][0];

    #pragma unroll 1
    for (int m = 0; m < MS; ++m) {
        const int mn = (m + 1 < MS) ? m + 1 : m;
        const float* np = nbase + (size_t)mn * ((size_t)NPART * 32);
        float4 nn0 = ((const float4*)np)[0];
        float4 nn1 = ((const float4*)np)[1];

        // B fragment: X -> packed bf16 (1 v_cvt_pk_bf16_f32 per pair)
        int4 bxw = make_int4((int)pk2(X[0], X[1]), (int)pk2(X[2], X[3]),
                             (int)pk2(X[4], X[5]), (int)pk2(X[6], X[7]));
        bfrag BX = __builtin_bit_cast(bfrag, bxw);

        const float s = (float)m * dt;

        // ---- GEMM1: 8 independent MFMAs, C-init ready at step start ----
        ffrag C[8];
        #pragma unroll
        for (int mt = 0; mt < 8; ++mt) {
            ffrag c;
            #pragma unroll
            for (int r = 0; r < 4; ++r) c[r] = fmaf(s, W1s[mt][r], Stat[mt][r]);
            C[mt] = c;
        }
        #pragma unroll
        for (int mt = 0; mt < 8; ++mt)
            C[mt] = __builtin_amdgcn_mfma_f32_16x16x32_bf16(A1[mt], BX, C[mt], 0, 0, 0);

        // ---- tanh + pack: C-regs become GEMM2 A-fragments directly ----
        uint2 Hpk[8];
        #pragma unroll
        for (int mt = 0; mt < 8; ++mt) {
            const unsigned u0 = pk2(fast_tanh(C[mt][0]), fast_tanh(C[mt][1]));
            const unsigned u1 = pk2(fast_tanh(C[mt][2]), fast_tanh(C[mt][3]));
            Hpk[mt] = make_uint2(u0, u1);
        }

        // ---- GEMM2: Z^T = H^T @ W2(kappa), two 2-deep chains per N-tile ----
        ffrag D0a = Z0i, D0b = Zzero, D1a = Z1i, D1b = Zzero;
        #pragma unroll
        for (int kt = 0; kt < 4; ++kt) {
            int4 aw = make_int4((int)Hpk[2 * kt].x, (int)Hpk[2 * kt].y,
                                (int)Hpk[2 * kt + 1].x, (int)Hpk[2 * kt + 1].y);
            bfrag A = __builtin_bit_cast(bfrag, aw);
            if (kt & 1) {
                D0b = __builtin_amdgcn_mfma_f32_16x16x32_bf16(A, B2[0][kt], D0b, 0, 0, 0);
                D1b = __builtin_amdgcn_mfma_f32_16x16x32_bf16(A, B2[1][kt], D1b, 0, 0, 0);
            } else {
                D0a = __builtin_amdgcn_mfma_f32_16x16x32_bf16(A, B2[0][kt], D0a, 0, 0, 0);
                D1a = __builtin_amdgcn_mfma_f32_16x16x32_bf16(A, B2[1][kt], D1a, 0, 0, 0);
            }
        }
        ffrag D0 = D0a + D0b;   // Z[particle 4q+r][outdim p]
        ffrag D1 = D1a + D1b;   // Z[particle 4q+r][outdim 16+p]

        // ---- scatter Z to [particle][dim], gather back in B-layout ----
        #pragma unroll
        for (int r = 0; r < 4; ++r) {
            float* zr = zbase + (4 * q + r) * 36;
            zr[p]      = D0[r];     // compiler fuses into ds_write2_b32
            zr[16 + p] = D1[r];
        }

        __builtin_amdgcn_wave_barrier();   // DS in-order per wave

        float4 z0 = *(const float4*)&zrow[8 * q];
        float4 z1 = *(const float4*)&zrow[8 * q + 4];
        float Z[8] = {z0.x, z0.y, z0.z, z0.w, z1.x, z1.y, z1.z, z1.w};
        float Nn[8] = {nc0.x, nc0.y, nc0.z, nc0.w, nc1.x, nc1.y, nc1.z, nc1.w};

        // V: (0.5-cr)*dt*sum(Z^2) + sqrt_dt*sum(Z*n)
        float s2 = 0.0f, sn = 0.0f;
        #pragma unroll
        for (int j = 0; j < 8; ++j) {
            s2 = fmaf(Z[j], Z[j], s2);
            sn = fmaf(Z[j], Nn[j], sn);
        }
        s2 += __shfl_xor(s2, 16); s2 += __shfl_xor(s2, 32);
        sn += __shfl_xor(sn, 16); sn += __shfl_xor(sn, 32);
        V = fmaf(kv, s2, fmaf(sqrt_dt, sn, V));

        // X = ax*X - bcr*Z + sqrt_dt*n
        #pragma unroll
        for (int j = 0; j < 8; ++j) {
            float t = fmaf(-bcr, Z[j], sqrt_dt * Nn[j]);
            X[j] = fmaf(ax, X[j], t);
        }

        nc0 = nn0; nc1 = nn1;

        __builtin_amdgcn_wave_barrier();   // protect Zlds WAR before next scatter
    }

    float4* xout = (float4*)(outX + (size_t)part * 32 + 8 * q);
    xout[0] = make_float4(X[0], X[1], X[2], X[3]);
    xout[1] = make_float4(X[4], X[5], X[6], X[7]);
    if (q == 0) outV[part] = V;
}

extern "C" void kernel_launch(void* const* d_in, const int* in_sizes, int n_in,
                              void* d_out, int out_size, void* d_ws, size_t ws_size,
                              hipStream_t stream) {
    const float* obs   = (const float*)d_in[0];
    const float* x0    = (const float*)d_in[1];
    const float* v0    = (const float*)d_in[2];
    const float* noise = (const float*)d_in[3];
    const float* W1    = (const float*)d_in[4];
    const float* b1    = (const float*)d_in[5];
    const float* W2    = (const float*)d_in[6];
    const float* b2    = (const float*)d_in[7];
    const float* th    = (const float*)d_in[8];
    const int*   oi    = (const int*)d_in[9];
    const int*   cr    = (const int*)d_in[10];

    float* outX = (float*)d_out;
    float* outV = outX + (size_t)NPART * 32;

    dim3 grid(NPART / 64);   // 512 blocks x 4 waves x 16 particles
    fused_sde_mfma<<<grid, BLOCK, 0, stream>>>(obs, x0, v0, noise, W1, b1, W2, b2,
                                               th, oi, cr, outX, outV);
}